// Round 5
// baseline (3438.718 us; speedup 1.0000x reference)
//
#include <hip/hip_runtime.h>

// Eikonal 2D: |grad u| = f, u(256,256)=0, Godunov upwind, converged fixed point.
//
// v5: fully asynchronous chaotic relaxation. v4's failure isolated the real
// cost model: with halo exchange once per KIN iters, a front crossing a tile
// boundary wastes ~KIN/2 iters per crossing; with KIN ~ tile width the waste
// is ~L/2 TOTAL regardless of tile size, so round-gated Jacobi needs ~1.5-2L
// ~= 1150-1400 virtual iters (v4 had 832 -> under-converged by 2%, absmax 8
// vs 6.88). Instead of paying, remove the quantization: exchange halos EVERY
// iteration and drop all barriers. Every update is a monotone min from BIG,
// so arbitrary staleness/interleaving is safe (converges from above); the
// barrier's only real job was defeating LDS register-caching, which relaxed
// workgroup-scope LDS atomics (plain ds_read/ds_write, uncacheable) do
// directly.
//
// Structure: v4's occupancy layout (16x16 tiles, 1024 blocks, 1 cell/thread,
// 4 blocks/CU = 16 waves/CU = 4 waves/SIMD). Horizontal neighbors via DPP
// (halo-in-`old` edge trick, own-wave registers, always fresh). Vertical via
// LDS atomics. Edge lanes: publish v every iter (relaxed agent store) and
// re-load their halo cell every iter through a DEPTH-2 software pipeline
// (consume the value loaded two iterations ago) so ~600cy LLC latency stays
// off the critical path. Per-iter floor ~ LDS pipe: 3 DS-ops x 16 waves x
// ~5.8cy ~= 280cy ~= 120ns per CU-iteration.
//
// Budget: chain ~ L(570 worst Manhattan geodesic) + ~4 iters slip per tile
// crossing (~36 crossings) ~= 715; ITERS=1200 -> 1.68x margin. Launch skew
// and wave-scheduling unfairness eat into margin far less than 0.68x.
// Under-convergence stays loudly caught (absmax blowup).

#define NG     512
#define TW     16
#define TH     16
#define BIGV   1e10f
#define SRC_I  256
#define SRC_J  256
#define ITERS  1200

#define LDS_LD(p)    __hip_atomic_load((p),      __ATOMIC_RELAXED, __HIP_MEMORY_SCOPE_WORKGROUP)
#define LDS_ST(p, x) __hip_atomic_store((p), (x), __ATOMIC_RELAXED, __HIP_MEMORY_SCOPE_WORKGROUP)
#define GLB_LD(p)    __hip_atomic_load((p),      __ATOMIC_RELAXED, __HIP_MEMORY_SCOPE_AGENT)
#define GLB_ST(p, x) __hip_atomic_store((p), (x), __ATOMIC_RELAXED, __HIP_MEMORY_SCOPE_AGENT)

// lane i gets lane i-1's x within each 16-lane DPP row; row-lane 0 (tx==0,
// tile left edge) keeps `edge` (bound_ctrl=false -> invalid src = old).
__device__ __forceinline__ float dpp_shr1(float x, float edge) {
    return __int_as_float(__builtin_amdgcn_update_dpp(
        __float_as_int(edge), __float_as_int(x), 0x111, 0xf, 0xf, false));
}
// lane i gets lane i+1's x; row-lane 15 (tx==15, tile right edge) keeps edge.
__device__ __forceinline__ float dpp_shl1(float x, float edge) {
    return __int_as_float(__builtin_amdgcn_update_dpp(
        __float_as_int(edge), __float_as_int(x), 0x101, 0xf, 0xf, false));
}

__global__ void eik_init(float* __restrict__ u) {
    int idx = blockIdx.x * blockDim.x + threadIdx.x;
    if (idx < NG * NG) u[idx] = (idx == SRC_I * NG + SRC_J) ? 0.0f : BIGV;
}

__global__ __launch_bounds__(256, 4) void eik_persist(const float* __restrict__ f,
                                                      float* __restrict__ u) {
    // rows 0 and TH+1 are N/S halo rows, refreshed every iteration
    __shared__ float S[TH + 2][TW];   // 1.125 KB

    const int tx = threadIdx.x;          // col 0..15 (fast dim: one DPP row)
    const int ty = threadIdx.y;          // row 0..15
    const int gi = blockIdx.y * TH + ty;
    const int gj = blockIdx.x * TW + tx;
    const int base = gi * NG + gj;

    const float fh = f[base];
    const float fq = 2.0f * fh * fh;

    float v = (gi == SRC_I && gj == SRC_J) ? 0.0f : BIGV;

    const bool etop = (ty == 0), ebot = (ty == TH - 1);
    const bool elft = (tx == 0), ergt = (tx == TW - 1);
    const bool hast = (gi > 0),  hasb = (gi < NG - 1);
    const bool hasl = (gj > 0),  hasr = (gj < NG - 1);
    const bool epub = etop || ebot || elft || ergt;

    S[ty + 1][tx] = v;
    if (etop) S[0][tx] = BIGV;
    if (ebot) S[TH + 1][tx] = BIGV;
    __syncthreads();   // one-time: init visible; no barriers after this

    // depth-2 pipelined halo registers: cX consumed this iter (loaded 2 iters
    // ago), nX in flight (loaded last iter). Non-edge lanes keep BIGV.
    float cN = BIGV, cS = BIGV, cW = BIGV, cE = BIGV;
    float nN = BIGV, nS = BIGV, nW = BIGV, nE = BIGV;

    for (int it = 0; it < ITERS; ++it) {
        // consume stage-0 halos (vmcnt for these completed ~2 iters ago)
        if (etop) LDS_ST(&S[0][tx], cN);
        if (ebot) LDS_ST(&S[TH + 1][tx], cS);
        const float hW = cW, hE = cE;
        // rotate pipeline and issue next loads (fire now, use in 2 iters)
        cN = nN; cS = nS; cW = nW; cE = nE;
        if (etop && hast) nN = GLB_LD(u + base - NG);
        if (ebot && hasb) nS = GLB_LD(u + base + NG);
        if (elft && hasl) nW = GLB_LD(u + base - 1);
        if (ergt && hasr) nE = GLB_LD(u + base + 1);

        // neighbors: vertical via LDS atomics, horizontal via DPP (own wave)
        const float up = LDS_LD(&S[ty][tx]);
        const float dn = LDS_LD(&S[ty + 2][tx]);
        const float lf = dpp_shr1(v, hW);
        const float rt = dpp_shl1(v, hE);

        float a  = fminf(up, dn);
        float b  = fminf(lf, rt);
        float s  = a - b;
        float u1 = fminf(a, b) + fh;                              // 1D update
        float t  = fmaxf(fmaf(-fabsf(s), fabsf(s), fq), 0.0f);    // 2fh^2-d^2
        float u2 = fmaf(0.5f, __builtin_amdgcn_sqrtf(t), 0.5f * (a + b));
        float un = (fabsf(s) >= fh) ? u1 : u2;                    // branch-free
        v = fminf(v, un);                                         // src stays 0

        LDS_ST(&S[ty + 1][tx], v);
        if (epub) GLB_ST(u + base, v);   // publish edge every iteration
    }

    // final write: agent-scope b32 store; same-thread same-address ordering
    // with the published edge stores is guaranteed
    GLB_ST(u + base, v);
}

extern "C" void kernel_launch(void* const* d_in, const int* in_sizes, int n_in,
                              void* d_out, int out_size, void* d_ws, size_t ws_size,
                              hipStream_t stream) {
    const float* f = (const float*)d_in[0];
    float* u = (float*)d_out;   // solution buffer + halo-exchange medium

    eik_init<<<(NG * NG + 1023) / 1024, 1024, 0, stream>>>(u);

    dim3 grid(NG / TW, NG / TH);   // (32, 32) = 1024 blocks = 4/CU
    dim3 block(16, 16);            // 256 threads = 4 waves, 1 cell/thread
    eik_persist<<<grid, block, 0, stream>>>(f, u);
}

// Round 6
// 347.780 us; speedup vs baseline: 9.8876x; 9.8876x over previous
//
#include <hip/hip_runtime.h>

// Eikonal 2D: |grad u| = f, u(256,256)=0, Godunov upwind, converged fixed point.
//
// v6: v5 proved per-iteration global halo exchange is dead on MI355X —
// agent-scope b32 halo traffic bypasses the (non-coherent) caches: 2.4 GB
// HBM fetch for a 1 MB buffer, per-iter wall = HBM-atomic latency (2.9 µs),
// VALUBusy 7.9%. Cross-tile exchange must stay at round granularity; only
// LDS/DPP may sit on the per-iteration path.
//
// So: v4's occupancy structure (1 cell/thread, 16x16 tiles, 1024 blocks =
// 4 blocks/CU = 16 waves/CU = 4 waves/SIMD, 4 mutually un-barriered blocks
// hiding each other's stalls) + v3's empirically PROVEN convergence schedule
// (ROUNDS=52 x KIN=16 sync halo rounds), with the horizontal transport v4
// lacked restored by TWO DPP-Jacobi substeps per barrier iteration: read
// up/dn from LDS once, then twice {lf/rt = DPP of current v; Godunov min}.
// Substeps are pure register+VALU (~65cy), so horizontal speed = 2 cols/iter
// BOTH directions >= v3's (1.5,1) on every axis at the identical schedule ->
// convergence dominates the proven-passing v3 (832 virtual iters, margin
// absmax 2.0 vs threshold 6.88). v4's failure (1,1 transport) is consistent:
// the horizontal boost is exactly what made 832 sufficient.
//
// Per-iter issue cost: VALU ~ 4 waves/SIMD x 31 ops x 2cy ~ 250cy; DS ~ 16
// waves x 2 instrs (ds_read2-fused up/dn + write) x 6cy ~ 190cy; ~300cy
// serial chain hidden across 4 independent blocks -> ~125ns/iter vs v3's
// 269ns. Monotone min-updates from BIG keep stale/racy halo reads harmless;
// under-convergence leaves big residuals (loudly caught by absmax).

#define NG     512
#define TW     16
#define TH     16
#define BIGV   1e10f
#define SRC_I  256
#define SRC_J  256
#define KIN    16
#define ROUNDS 52

// lane i gets lane i-1's x within each 16-lane DPP row; row-lane 0 (tx==0,
// tile left edge) keeps `edge` (bound_ctrl=false -> invalid src = old).
__device__ __forceinline__ float dpp_shr1(float x, float edge) {
    return __int_as_float(__builtin_amdgcn_update_dpp(
        __float_as_int(edge), __float_as_int(x), 0x111, 0xf, 0xf, false));
}
// lane i gets lane i+1's x; row-lane 15 (tx==15, tile right edge) keeps edge.
__device__ __forceinline__ float dpp_shl1(float x, float edge) {
    return __int_as_float(__builtin_amdgcn_update_dpp(
        __float_as_int(edge), __float_as_int(x), 0x101, 0xf, 0xf, false));
}

__global__ void eik_init(float* __restrict__ u) {
    int idx = blockIdx.x * blockDim.x + threadIdx.x;
    if (idx < NG * NG) u[idx] = (idx == SRC_I * NG + SRC_J) ? 0.0f : BIGV;
}

__global__ __launch_bounds__(256, 4) void eik_persist(const float* __restrict__ f,
                                                      float* __restrict__ u) {
    // rows 0 and TH+1 are the N/S halo rows, refreshed once per round
    __shared__ float S[TH + 2][TW];   // 1.125 KB

    const int tx = threadIdx.x;          // col 0..15 (fast dim: one DPP row)
    const int ty = threadIdx.y;          // row 0..15
    const int gi = blockIdx.y * TH + ty;
    const int gj = blockIdx.x * TW + tx;
    const int base = gi * NG + gj;

    const float fh = f[base];
    const float fq = 2.0f * fh * fh;

    float v = (gi == SRC_I && gj == SRC_J) ? 0.0f : BIGV;

    const bool etop = (ty == 0), ebot = (ty == TH - 1);
    const bool elft = (tx == 0), ergt = (tx == TW - 1);
    const bool hast = (gi > 0),  hasb = (gi < NG - 1);
    const bool hasl = (gj > 0),  hasr = (gj < NG - 1);
    const bool epub = etop || ebot || elft || ergt;

    S[ty + 1][tx] = v;

    // Godunov upwind local update: a = min(up,dn) precomputed (frozen within
    // the iteration), b from horizontal neighbors; monotone min into v.
    auto upd = [&](float a, float lf, float rt) {
        float b  = fminf(lf, rt);
        float s  = a - b;
        float u1 = fminf(a, b) + fh;                              // 1D update
        float t  = fmaxf(fmaf(-fabsf(s), fabsf(s), fq), 0.0f);    // 2fh^2-d^2
        float u2 = fmaf(0.5f, __builtin_amdgcn_sqrtf(t), 0.5f * (a + b));
        float un = (fabsf(s) >= fh) ? u1 : u2;                    // branch-free
        v = fminf(v, un);                                         // src stays 0
    };

    for (int r = 0; r < ROUNDS; ++r) {
        // --- halo refresh (device scope; per-XCD L2s not coherent) ---
        float hW = BIGV, hE = BIGV;
        if (etop)
            S[0][tx] = hast
                ? __hip_atomic_load(u + base - NG, __ATOMIC_RELAXED, __HIP_MEMORY_SCOPE_AGENT)
                : BIGV;
        if (ebot)
            S[TH + 1][tx] = hasb
                ? __hip_atomic_load(u + base + NG, __ATOMIC_RELAXED, __HIP_MEMORY_SCOPE_AGENT)
                : BIGV;
        if (elft && hasl) hW = __hip_atomic_load(u + base - 1, __ATOMIC_RELAXED, __HIP_MEMORY_SCOPE_AGENT);
        if (ergt && hasr) hE = __hip_atomic_load(u + base + 1, __ATOMIC_RELAXED, __HIP_MEMORY_SCOPE_AGENT);
        __syncthreads();   // halo rows visible before first inner iteration

        // --- KIN barrier iterations, 2 register substeps each ---
        for (int it = 0; it < KIN; ++it) {
            const float up = S[ty][tx];        // ds_read2_b32 pair
            const float dn = S[ty + 2][tx];    // (offsets 0 / +32 dwords)
            const float a  = fminf(up, dn);    // frozen for both substeps

            // substep 1: horizontal neighbors = current v via DPP
            upd(a, dpp_shr1(v, hW), dpp_shl1(v, hE));
            // substep 2: post-substep-1 neighbors (wave lockstep) ->
            // horizontal transport 2 cols/iter in both directions
            upd(a, dpp_shr1(v, hW), dpp_shl1(v, hE));

            S[ty + 1][tx] = v;
            __syncthreads();
        }

        // --- publish tile edges (device scope) ---
        if (epub)
            __hip_atomic_store(u + base, v, __ATOMIC_RELAXED, __HIP_MEMORY_SCOPE_AGENT);
    }

    // final write: agent-scope b32 store; same-thread same-address ordering
    // with the published edge stores is guaranteed
    __hip_atomic_store(u + base, v, __ATOMIC_RELAXED, __HIP_MEMORY_SCOPE_AGENT);
}

extern "C" void kernel_launch(void* const* d_in, const int* in_sizes, int n_in,
                              void* d_out, int out_size, void* d_ws, size_t ws_size,
                              hipStream_t stream) {
    const float* f = (const float*)d_in[0];
    float* u = (float*)d_out;   // solution buffer + halo-exchange medium

    eik_init<<<(NG * NG + 1023) / 1024, 1024, 0, stream>>>(u);

    dim3 grid(NG / TW, NG / TH);   // (32, 32) = 1024 blocks = 4/CU
    dim3 block(16, 16);            // 256 threads = 4 waves, 1 cell/thread
    eik_persist<<<grid, block, 0, stream>>>(f, u);
}

// Round 8
// 296.794 us; speedup vs baseline: 11.5862x; 1.1718x over previous
//
#include <hip/hip_runtime.h>

// Eikonal 2D: |grad u| = f, u(256,256)=0, Godunov upwind, converged fixed point.
//
// v8 = v7 with the fatal staleness bug fixed. v7's halo prefetch at iter 13
// read neighbor edges BEFORE their end-of-round publish -> halo data was 2
// rounds old -> cross-tile hop latency doubled -> absmax 48. Fix: fresh halo
// load at ROUND START (v3/v6's proven pattern). With that, the calibrated
// virtual-iteration model (need ~ 256/sh + 256/sv + crossings*KIN/2) fits
// every observation: v4 768/832 FAIL, v3 619/832 pass, v6 640/832 pass.
// This structure (sh=1, sv=1.5): need ~683 -> ROUNDS=60 gives 960 virtual
// iters = 1.41x margin (> v6's proven 1.30x).
//
// Structure (v7): 16x16 tiles, 128-thread (2-wave) blocks, VERTICAL
// in-register pairs (tx=0..15 = one full 16-lane DPP row, edge old-trick
// exact; ty=0..7 pair rows). 1024 blocks = 4/CU = 8 waves/CU in 4
// INDEPENDENT 2-wave barrier groups hiding each other's stalls. 1 Godunov
// upd/cell/iter (the v6-measured cost law: wall ~ total upds / busy%).
// Per iter: 1 ds_read2_b32 (up/dn) + 1 ds_write2_b32 (own pair) + 4 DPP +
// 2 UPD. LDS row stride 24 dwords -> only 2-way bank aliasing (free, m136).
// Vertical transport 1.5/iter via in-pair alternating GS; horizontal 1/iter
// via DPP Jacobi.
//
// __syncthreads() per iteration: with fresh-halo rounds there are no
// outstanding global loads mid-round, so its vmcnt(0) drain is free, and it
// removes all inline-asm-barrier reordering risk. N/S halo staging is
// same-lane (ty==0 stages+reads row 0; ty==7 stages+reads row 17), W/E
// halos live in registers consumed by the DPP old-operand -> no extra sync.
// Monotone min-updates from BIG keep stale/racy halo reads harmless;
// under-convergence leaves big residuals (loudly caught by absmax).

#define NG     512
#define TS     16
#define BIGV   1e10f
#define SRC_I  256
#define SRC_J  256
#define KIN    16
#define ROUNDS 60
#define LSTR   24          // LDS row stride (dwords): 2-way bank aliasing only

#define GLB_LD(p)    __hip_atomic_load((p),      __ATOMIC_RELAXED, __HIP_MEMORY_SCOPE_AGENT)
#define GLB_ST(p, x) __hip_atomic_store((p), (x), __ATOMIC_RELAXED, __HIP_MEMORY_SCOPE_AGENT)

// lane i gets lane i-1's x within each 16-lane DPP row; row-lane 0 (tx==0,
// tile left edge) keeps `edge` (bound_ctrl=false -> invalid src = old).
__device__ __forceinline__ float dpp_shr1(float x, float edge) {
    return __int_as_float(__builtin_amdgcn_update_dpp(
        __float_as_int(edge), __float_as_int(x), 0x111, 0xf, 0xf, false));
}
// lane i gets lane i+1's x; row-lane 15 (tx==15, tile right edge) keeps edge.
__device__ __forceinline__ float dpp_shl1(float x, float edge) {
    return __int_as_float(__builtin_amdgcn_update_dpp(
        __float_as_int(edge), __float_as_int(x), 0x101, 0xf, 0xf, false));
}

__global__ void eik_init(float* __restrict__ u) {
    int idx = blockIdx.x * blockDim.x + threadIdx.x;
    if (idx < NG * NG) u[idx] = (idx == SRC_I * NG + SRC_J) ? 0.0f : BIGV;
}

__global__ __launch_bounds__(128, 2) void eik_persist(const float* __restrict__ f,
                                                      float* __restrict__ u) {
    // storage row (cr+1) holds cell row cr; rows 0 and TS+1 are N/S halos
    __shared__ float S[(TS + 2) * LSTR];   // 1.7 KB

    const int tx = threadIdx.x;          // col 0..15 (one full DPP row)
    const int ty = threadIdx.y;          // pair-row 0..7
    const int r0 = 2 * ty;               // cell rows r0, r0+1
    const int gi0  = blockIdx.y * TS + r0;
    const int gj   = blockIdx.x * TS + tx;
    const int base0 = gi0 * NG + gj;
    const int base1 = base0 + NG;

    const float fh0 = f[base0], fh1 = f[base1];
    const float fq0 = 2.0f * fh0 * fh0, fq1 = 2.0f * fh1 * fh1;

    float v0 = (gi0     == SRC_I && gj == SRC_J) ? 0.0f : BIGV;
    float v1 = (gi0 + 1 == SRC_I && gj == SRC_J) ? 0.0f : BIGV;

    const bool pn = (ty == 0), ps = (ty == TS / 2 - 1);   // pair touches N/S edge
    const bool el = (tx == 0), er = (tx == TS - 1);
    const bool hast = (gi0 > 0), hasb = (gi0 + 2 < NG);
    const bool hasl = (gj > 0),  hasr = (gj + 1 < NG);

    // LDS addresses (dword indices), loop-invariant
    const int aUP = (r0)     * LSTR + tx;   // stored row of cell r0-1 (or N halo)
    const int aDN = (r0 + 3) * LSTR + tx;   // stored row of cell r0+2 (or S halo)
    const int aW0 = (r0 + 1) * LSTR + tx;   // own cell 0
    const int aW1 = (r0 + 2) * LSTR + tx;   // own cell 1

    S[aW0] = v0;
    S[aW1] = v1;
    if (pn) S[0 * LSTR + tx] = BIGV;
    if (ps) S[(TS + 1) * LSTR + tx] = BIGV;
    __syncthreads();

    // Godunov upwind local update (monotone min into vv; source stays 0)
#define UPD(vv, au, ad, lf, rt, fh_, fq_)                                   \
    do {                                                                    \
        float a  = fminf((au), (ad));                                       \
        float b  = fminf((lf), (rt));                                       \
        float s  = a - b;                                                   \
        float u1 = fminf(a, b) + (fh_);                                     \
        float t  = fmaf(-fabsf(s), fabsf(s), (fq_));   /* may be <0 */      \
        float u2 = fmaf(0.5f, __builtin_amdgcn_sqrtf(t), 0.5f * (a + b));   \
        float un = (fabsf(s) >= (fh_)) ? u1 : u2;      /* NaN discarded */  \
        (vv) = fminf((vv), un);                                             \
    } while (0)

    for (int r = 0; r < ROUNDS; ++r) {
        // --- FRESH halo load + stage (device scope; L2s not coherent) ---
        // N/S staging is same-lane (stager == reader), W/E stay in registers
        // consumed via the DPP old-operand -> no sync needed before iter 0.
        float hW0 = BIGV, hW1 = BIGV, hE0 = BIGV, hE1 = BIGV;
        if (pn) S[0 * LSTR + tx] =
            hast ? GLB_LD(u + base0 - NG) : BIGV;
        if (ps) S[(TS + 1) * LSTR + tx] =
            hasb ? GLB_LD(u + base1 + NG) : BIGV;
        if (el && hasl) { hW0 = GLB_LD(u + base0 - 1);
                          hW1 = GLB_LD(u + base1 - 1); }
        if (er && hasr) { hE0 = GLB_LD(u + base0 + 1);
                          hE1 = GLB_LD(u + base1 + 1); }

        // --- KIN barrier iterations, in-pair vertical GS alternating ---
        for (int it = 0; it < KIN; ++it) {
            const float up = S[aUP];   // cross-pair / halo (ds_read2 pair)
            const float dn = S[aDN];
            const float lf0 = dpp_shr1(v0, hW0), rt0 = dpp_shl1(v0, hE0);
            const float lf1 = dpp_shr1(v1, hW1), rt1 = dpp_shl1(v1, hE1);

            if ((it & 1) == 0) {   // downward: v0 then v1 (uses new v0)
                UPD(v0, up, v1, lf0, rt0, fh0, fq0);
                UPD(v1, v0, dn, lf1, rt1, fh1, fq1);
            } else {               // upward: v1 then v0 (uses new v1)
                UPD(v1, v0, dn, lf1, rt1, fh1, fq1);
                UPD(v0, up, v1, lf0, rt0, fh0, fq0);
            }

            S[aW0] = v0;           // ds_write2 pair
            S[aW1] = v1;
            __syncthreads();       // no outstanding globals -> drain is free
        }

        // --- publish tile edges (device scope) ---
        if (pn) GLB_ST(u + base0, v0);
        if (ps) GLB_ST(u + base1, v1);
        if (el || er) { GLB_ST(u + base0, v0); GLB_ST(u + base1, v1); }
    }

    // final write: agent-scope b32 stores; same-thread same-address ordering
    // with the published edge stores is guaranteed
    GLB_ST(u + base0, v0);
    GLB_ST(u + base1, v1);
#undef UPD
}

extern "C" void kernel_launch(void* const* d_in, const int* in_sizes, int n_in,
                              void* d_out, int out_size, void* d_ws, size_t ws_size,
                              hipStream_t stream) {
    const float* f = (const float*)d_in[0];
    float* u = (float*)d_out;   // solution buffer + halo-exchange medium

    eik_init<<<(NG * NG + 1023) / 1024, 1024, 0, stream>>>(u);

    dim3 grid(NG / TS, NG / TS);   // (32, 32) = 1024 blocks = 4/CU
    dim3 block(16, 8);             // 128 threads = 2 waves, 2 cells/thread
    eik_persist<<<grid, block, 0, stream>>>(f, u);
}

// Round 11
// 294.680 us; speedup vs baseline: 11.6693x; 1.0072x over previous
//
#include <hip/hip_runtime.h>

// Eikonal 2D: |grad u| = f, u(256,256)=0, Godunov upwind, converged fixed point.
//
// v11 = v10's fast engine + v8's proven halo timing. The hop-latency model
// (calibrated on v4/v7/v8/v10): per-tile-hop = ceil((T/s + d)/KIN)*KIN where
// d = halo consumption delay. Horizontal axis has ZERO slack (T/sh = 16/1 =
// KIN), so v10's d=4 doubled horizontal hop latency 16->32 (+256 need) ->
// knife-edge at budget 960 (absmax 6.0 pass / 8.0 replay fail). Vertical has
// slack (T/sv=10.7). Fix: consume halos at ITER 0 (d=0, v8 semantics) —
// issue + stage at round start, eat the ~700-900cy vmcnt stall once per 16
// iters (~45cy/iter amortized, partially hidden by the other 3 blocks/CU).
// Transport = v8-identical + <=32 need for the 2-iter wave-interface
// granularity. Budget ROUNDS=62 (992) vs need ~830 -> margin ~1.20 (v8's
// proven class; v8's clean absmax 2.0 = bf16 floor implies headroom).
//
// Engine (v10, measured ~197us/60 rounds): 16x16 tiles, 1024 blocks = 4/CU,
// 128-thread (2-wave) blocks, vertical in-register pairs (tx=0..15 = one
// 16-lane DPP row, edge old-operand trick; ty=0..7 pair rows), in-pair
// alternating GS (sv=1.5, sh=1 via DPP Jacobi), LDS stride 24 dwords (2-way
// bank aliasing = free), 1 Godunov upd/cell/iter, RAW barrier (lgkmcnt(0) +
// s_barrier, NO vmcnt drain) every 2 iters bounding cross-wave drift <=2.
// All LDS traffic is relaxed workgroup-scope atomics (plain ds_read/write,
// never register-cached; safe against hoisting across the asm barrier).
// N/S halo rows are single-owner (stager == only reader, same wave) -> no
// staging sync. Monotone min-from-BIG keeps every stale/racy read harmless;
// under-convergence is loudly caught by absmax.

#define NG     512
#define TS     16
#define BIGV   1e10f
#define SRC_I  256
#define SRC_J  256
#define KIN    16
#define ROUNDS 62
#define LSTR   24          // LDS row stride (dwords): 2-way bank aliasing only

#define GLB_LD(p)    __hip_atomic_load((p),      __ATOMIC_RELAXED, __HIP_MEMORY_SCOPE_AGENT)
#define GLB_ST(p, x) __hip_atomic_store((p), (x), __ATOMIC_RELAXED, __HIP_MEMORY_SCOPE_AGENT)
#define LDS_LD(p)    __hip_atomic_load((p),      __ATOMIC_RELAXED, __HIP_MEMORY_SCOPE_WORKGROUP)
#define LDS_ST(p, x) __hip_atomic_store((p), (x), __ATOMIC_RELAXED, __HIP_MEMORY_SCOPE_WORKGROUP)

// raw workgroup barrier: DS ops drained (cross-wave visibility), but NO
// vmcnt drain -> global loads/stores stay in flight across it
#define SYNC()                                                  \
    do {                                                        \
        asm volatile("s_waitcnt lgkmcnt(0)" ::: "memory");      \
        __builtin_amdgcn_s_barrier();                           \
    } while (0)

// lane i gets lane i-1's x within each 16-lane DPP row; row-lane 0 (tx==0,
// tile left edge) keeps `edge` (bound_ctrl=false -> invalid src = old).
__device__ __forceinline__ float dpp_shr1(float x, float edge) {
    return __int_as_float(__builtin_amdgcn_update_dpp(
        __float_as_int(edge), __float_as_int(x), 0x111, 0xf, 0xf, false));
}
// lane i gets lane i+1's x; row-lane 15 (tx==15, tile right edge) keeps edge.
__device__ __forceinline__ float dpp_shl1(float x, float edge) {
    return __int_as_float(__builtin_amdgcn_update_dpp(
        __float_as_int(edge), __float_as_int(x), 0x101, 0xf, 0xf, false));
}

__global__ void eik_init(float* __restrict__ u) {
    int idx = blockIdx.x * blockDim.x + threadIdx.x;
    if (idx < NG * NG) u[idx] = (idx == SRC_I * NG + SRC_J) ? 0.0f : BIGV;
}

__global__ __launch_bounds__(128, 2) void eik_persist(const float* __restrict__ f,
                                                      float* __restrict__ u) {
    // storage row (cr+1) holds cell row cr; rows 0 and TS+1 are N/S halos
    __shared__ float S[(TS + 2) * LSTR];   // 1.7 KB

    const int tx = threadIdx.x;          // col 0..15 (one full DPP row)
    const int ty = threadIdx.y;          // pair-row 0..7
    const int r0 = 2 * ty;               // cell rows r0, r0+1
    const int gi0  = blockIdx.y * TS + r0;
    const int gj   = blockIdx.x * TS + tx;
    const int base0 = gi0 * NG + gj;
    const int base1 = base0 + NG;

    const float fh0 = f[base0], fh1 = f[base1];
    const float fq0 = 2.0f * fh0 * fh0, fq1 = 2.0f * fh1 * fh1;

    float v0 = (gi0     == SRC_I && gj == SRC_J) ? 0.0f : BIGV;
    float v1 = (gi0 + 1 == SRC_I && gj == SRC_J) ? 0.0f : BIGV;

    const bool pn = (ty == 0), ps = (ty == TS / 2 - 1);   // pair touches N/S edge
    const bool el = (tx == 0), er = (tx == TS - 1);
    const bool hast = (gi0 > 0), hasb = (gi0 + 2 < NG);
    const bool hasl = (gj > 0),  hasr = (gj + 1 < NG);

    // LDS addresses (dword indices), loop-invariant
    const int aUP = (r0)     * LSTR + tx;   // stored row of cell r0-1 (or N halo)
    const int aDN = (r0 + 3) * LSTR + tx;   // stored row of cell r0+2 (or S halo)
    const int aW0 = (r0 + 1) * LSTR + tx;   // own cell 0
    const int aW1 = (r0 + 2) * LSTR + tx;   // own cell 1

    LDS_ST(&S[aW0], v0);
    LDS_ST(&S[aW1], v1);
    if (pn) LDS_ST(&S[0 * LSTR + tx], BIGV);
    if (ps) LDS_ST(&S[(TS + 1) * LSTR + tx], BIGV);
    __syncthreads();   // one-time init fence

    // W/E halo registers consumed via the DPP old-operand trick
    float hW0 = BIGV, hW1 = BIGV, hE0 = BIGV, hE1 = BIGV;

    // Godunov upwind local update (monotone min into vv; source stays 0)
#define UPD(vv, au, ad, lf, rt, fh_, fq_)                                   \
    do {                                                                    \
        float a  = fminf((au), (ad));                                       \
        float b  = fminf((lf), (rt));                                       \
        float s  = a - b;                                                   \
        float u1 = fminf(a, b) + (fh_);                                     \
        float t  = fmaf(-fabsf(s), fabsf(s), (fq_));   /* may be <0 */      \
        float u2 = fmaf(0.5f, __builtin_amdgcn_sqrtf(t), 0.5f * (a + b));   \
        float un = (fabsf(s) >= (fh_)) ? u1 : u2;      /* NaN discarded */  \
        (vv) = fminf((vv), un);                                             \
    } while (0)

    // two iterations (downward GS, then upward GS) + bounded-drift barrier
#define ITER_PAIR()                                                         \
    do {                                                                    \
        {   /* downward: v0 then v1 (uses new v0) */                        \
            float up = LDS_LD(&S[aUP]);                                     \
            float dn = LDS_LD(&S[aDN]);                                     \
            float lf0 = dpp_shr1(v0, hW0), rt0 = dpp_shl1(v0, hE0);         \
            float lf1 = dpp_shr1(v1, hW1), rt1 = dpp_shl1(v1, hE1);         \
            UPD(v0, up, v1, lf0, rt0, fh0, fq0);                            \
            UPD(v1, v0, dn, lf1, rt1, fh1, fq1);                            \
            LDS_ST(&S[aW0], v0);                                            \
            LDS_ST(&S[aW1], v1);                                            \
        }                                                                   \
        {   /* upward: v1 then v0 (uses new v1) */                          \
            float up = LDS_LD(&S[aUP]);                                     \
            float dn = LDS_LD(&S[aDN]);                                     \
            float lf0 = dpp_shr1(v0, hW0), rt0 = dpp_shl1(v0, hE0);         \
            float lf1 = dpp_shr1(v1, hW1), rt1 = dpp_shl1(v1, hE1);         \
            UPD(v1, v0, dn, lf1, rt1, fh1, fq1);                            \
            UPD(v0, up, v1, lf0, rt0, fh0, fq0);                            \
            LDS_ST(&S[aW0], v0);                                            \
            LDS_ST(&S[aW1], v1);                                            \
        }                                                                   \
        SYNC();                                                             \
    } while (0)

    for (int r = 0; r < ROUNDS; ++r) {
        // --- fresh halo: issue AND consume at round start (d=0; the ~700-
        // 900cy vmcnt stall amortizes to ~45cy/iter and is partially hidden
        // by the other co-resident blocks). N/S halo rows are single-owner
        // (stager == only reader, same wave); W/E are per-lane registers
        // consumed via the DPP old-operand -> no staging sync needed.
        if (pn) LDS_ST(&S[0 * LSTR + tx],
                       hast ? GLB_LD(u + base0 - NG) : BIGV);
        if (ps) LDS_ST(&S[(TS + 1) * LSTR + tx],
                       hasb ? GLB_LD(u + base1 + NG) : BIGV);
        hW0 = (el && hasl) ? GLB_LD(u + base0 - 1) : BIGV;
        hW1 = (el && hasl) ? GLB_LD(u + base1 - 1) : BIGV;
        hE0 = (er && hasr) ? GLB_LD(u + base0 + 1) : BIGV;
        hE1 = (er && hasr) ? GLB_LD(u + base1 + 1) : BIGV;

        ITER_PAIR();   // iters 0,1
        ITER_PAIR();   // iters 2,3
        ITER_PAIR();   // iters 4,5
        ITER_PAIR();   // iters 6,7
        ITER_PAIR();   // iters 8,9
        ITER_PAIR();   // iters 10,11
        ITER_PAIR();   // iters 12,13
        ITER_PAIR();   // iters 14,15

        // --- publish tile edges (device scope, fire-and-forget) ---
        if (pn) GLB_ST(u + base0, v0);
        if (ps) GLB_ST(u + base1, v1);
        if (el || er) { GLB_ST(u + base0, v0); GLB_ST(u + base1, v1); }
    }

    // final write: agent-scope b32 stores; same-thread same-address ordering
    // with the published edge stores is guaranteed
    GLB_ST(u + base0, v0);
    GLB_ST(u + base1, v1);
#undef ITER_PAIR
#undef UPD
}

extern "C" void kernel_launch(void* const* d_in, const int* in_sizes, int n_in,
                              void* d_out, int out_size, void* d_ws, size_t ws_size,
                              hipStream_t stream) {
    const float* f = (const float*)d_in[0];
    float* u = (float*)d_out;   // solution buffer + halo-exchange medium

    eik_init<<<(NG * NG + 1023) / 1024, 1024, 0, stream>>>(u);

    dim3 grid(NG / TS, NG / TS);   // (32, 32) = 1024 blocks = 4/CU
    dim3 block(16, 8);             // 128 threads = 2 waves, 2 cells/thread
    eik_persist<<<grid, block, 0, stream>>>(f, u);
}